// Round 5
// baseline (320.591 us; speedup 1.0000x reference)
//
#include <hip/hip_runtime.h>
#include <math.h>

#define N_TOKENS    16384
#define MODEL_DIM   2048
#define NUM_EXPERTS 64
#define NK          (N_TOKENS * 2)          // 32768

// d_out layout (float32 elements)
#define OFF_TOKEN_ORDER 0
#define OFF_REVERSED    (NK)                // 32768
#define OFF_COMBINE     (2 * NK)            // 65536
#define OFF_SPLITS      (3 * NK)            // 98304
#define OFF_PROBS       (3 * NK + NUM_EXPERTS)

#define NSEG 256
#define NFRAG 16384            // 64 ksteps * 4 tiles * 64 lanes

#define BUF_BYTES 32768        // 32 chunks of 1KB per kstep-pair (B 16KB + A 16KB)

typedef _Float16 half8 __attribute__((ext_vector_type(8)));
typedef float    f32x4 __attribute__((ext_vector_type(4)));

#define MEMFENCE asm volatile("" ::: "memory")

// ---------------------------------------------------------------------------
// Kernel 1: pre-split W into f16 hi/lo MFMA fragments (W scaled x64 so hi is
// never f16-denormal; lo is the x4096-scaled exact residual). Also zeroes
// segHist. Fragment fr = (kstep*4 + tile)*64 + lane holds 8 f16 of
// W[tile*16 + (lane&15)][kstep*32 + (lane>>4)*8 + 0..7].
// ---------------------------------------------------------------------------
__global__ __launch_bounds__(256) void preconvert(
    const float* __restrict__ w, half8* __restrict__ WH, half8* __restrict__ WL,
    int* __restrict__ segHist)
{
    const int fr = blockIdx.x * 256 + threadIdx.x;   // 0..16383
    const int lane = fr & 63;
    const int tile = (fr >> 6) & 3;
    const int kstep = fr >> 8;
    const int e = tile * 16 + (lane & 15);
    const int kb = kstep * 32 + (lane >> 4) * 8;
    const float* src = w + (size_t)e * MODEL_DIM + kb;
    const float4 w0 = *(const float4*)(src);
    const float4 w1 = *(const float4*)(src + 4);
    const float av[8] = {w0.x, w0.y, w0.z, w0.w, w1.x, w1.y, w1.z, w1.w};
    half8 hh, hl;
#pragma unroll
    for (int j = 0; j < 8; j++) {
        const float v = av[j] * 64.0f;
        const _Float16 h = (_Float16)v;
        hh[j] = h;
        hl[j] = (_Float16)((v - (float)h) * 4096.0f);
    }
    WH[fr] = hh;
    WL[fr] = hl;
    segHist[fr] = 0;        // NSEG*NUM_EXPERTS == 16384 exactly
}

// ---------------------------------------------------------------------------
// Kernel 2: fused gate v3 — traffic-minimal. Grid 256 blocks x 512 threads
// (8 waves = 4 token-groups x 2 K-halves). 64 tokens/block.
//
// The round-2..4 wall was VMEM VOLUME: per-wave B re-reads made 384-640MB of
// cache traffic (~5-8 TB/s service ceiling -> 77-80us). Here B is staged ONCE
// per block into LDS and shared by all 8 waves: total global traffic =
// X 128MB (once, HBM) + B 256 blocks x 512KB = 128MB (L2) = 256MB.
//
// Per kstep-pair j (K=32 per kh-half, 32 iters): 32KB staged as 32 contiguous
// 1KB chunks (16 B-frag chunks, 16 A chunks of 8 rows x 128B, XOR-16B
// write-side swizzle). Each wave: 4 global_load_dwordx4 -> regs (depth-2
// RA/RB pipeline, counted vmcnt(4), never drained), 4 ds_write_b128, ONE raw
// s_barrier per kstep (load-issue overlaps barrier wait), 10 ds_read_b128,
// 12 MFMA. fp64 fold every 8 ksteps; cross-kh fp64 reduce through aliased
// LDS; verified softmax/top2/combine/hist epilogue.
// Numerics bit-identical to rounds 1-4: logit=(accH+accC/4096)/64, W x64.
// ---------------------------------------------------------------------------
__global__ __launch_bounds__(512, 2) void gate_fused(
    const float* __restrict__ x, const half8* __restrict__ WH,
    const half8* __restrict__ WL, float* __restrict__ out,
    int* __restrict__ flat_idx, int* __restrict__ segHist)
{
    __shared__ alignas(16) unsigned char smem[2 * BUF_BYTES];   // 64KB

    const int tid  = threadIdx.x;
    const int wv   = tid >> 6;          // 0..7
    const int lane = tid & 63;
    const int kh   = wv & 1;            // K-half
    const int tg   = wv >> 1;           // token-group (0..3)
    const int t0   = blockIdx.x * 64;
    const int col  = lane & 15;
    const int kg   = lane >> 4;

    // ---- staging: wave wv owns chunks {wv, wv+8, wv+16, wv+24} ----
    // chunks 0..15: B (kh=c>>3, tile=(c>>1)&3, hl=c&1), lane*16 linear dest.
    // chunks 16..31: A (kh=(c-16)>>3, rowgrp=(c-16)&7): 8 rows x 128B,
    //                16B pieces XOR-swizzled at the ds_write address.
    const char* pSrc[4];
    {
        const int hl = wv & 1, tile = (wv >> 1) & 3;
        pSrc[0] = (const char*)((hl ? WL : WH) + ((size_t)(0 * 128 + tile) * 64 + lane));
        pSrc[1] = (const char*)((hl ? WL : WH) + ((size_t)(1 * 128 + tile) * 64 + lane));
        const int row = t0 + wv * 8 + (lane >> 3);
        pSrc[2] = (const char*)(x + (size_t)row * MODEL_DIM + (lane & 7) * 4);
        pSrc[3] = (const char*)(x + (size_t)row * MODEL_DIM + 1024 + (lane & 7) * 4);
    }
    const int sStr[4] = {4096, 4096, 128, 128};
    int dOff[4];
    {
        const int swz = (lane >> 3) * 128 + (((lane & 7) ^ (lane >> 3)) << 4);
        dOff[0] = wv * 1024 + lane * 16;
        dOff[1] = (wv + 8) * 1024 + lane * 16;
        dOff[2] = (16 + wv) * 1024 + swz;
        dOff[3] = (24 + wv) * 1024 + swz;
    }

    // ---- reader offsets ----
    int bOff[8];
#pragma unroll
    for (int t = 0; t < 4; t++)
#pragma unroll
        for (int hl = 0; hl < 2; hl++)
            bOff[t * 2 + hl] = (kh * 8 + t * 2 + hl) * 1024 + lane * 16;
    const int chunkA = 16 + kh * 8 + tg * 2 + (col >> 3);
    const int rowin  = col & 7;
    const int aoff0  = chunkA * 1024 + rowin * 128 + (((2 * kg)     ^ rowin) << 4);
    const int aoff1  = chunkA * 1024 + rowin * 128 + (((2 * kg + 1) ^ rowin) << 4);

    f32x4 accH[4], accC[4];
    double accD[4][4];
#pragma unroll
    for (int t = 0; t < 4; t++) {
        accH[t] = (f32x4){0.f, 0.f, 0.f, 0.f};
        accC[t] = (f32x4){0.f, 0.f, 0.f, 0.f};
#pragma unroll
        for (int r = 0; r < 4; r++) accD[t][r] = 0.0;
    }

    float4 RA[4], RB[4];

    // prologue: loads(0)->RA, loads(1)->RB, write RA->buf0
#pragma unroll
    for (int i = 0; i < 4; i++) RA[i] = *(const float4*)(pSrc[i]);
#pragma unroll
    for (int i = 0; i < 4; i++) RB[i] = *(const float4*)(pSrc[i] + sStr[i]);
    asm volatile("s_waitcnt vmcnt(4)" ::: "memory");           // loads(0) landed
#pragma unroll
    for (int i = 0; i < 4; i++) *(float4*)(smem + dOff[i]) = RA[i];

#define ITER(RI, RW, CB, WB, T, DOFOLD) do {                                 \
    const int jn_ = ((T) < 30) ? (T) + 2 : 31;                               \
    _Pragma("unroll")                                                        \
    for (int i_ = 0; i_ < 4; i_++)                                           \
        RI[i_] = *(const float4*)(pSrc[i_] + (size_t)jn_ * sStr[i_]);        \
    asm volatile("s_waitcnt lgkmcnt(0)" ::: "memory");                       \
    __builtin_amdgcn_s_barrier();                                            \
    MEMFENCE;                                                                \
    const unsigned char* buf_ = smem + (CB) * BUF_BYTES;                     \
    const float4 a0_ = *(const float4*)(buf_ + aoff0);                       \
    const float4 a1_ = *(const float4*)(buf_ + aoff1);                       \
    const float av_[8] = {a0_.x, a0_.y, a0_.z, a0_.w,                        \
                          a1_.x, a1_.y, a1_.z, a1_.w};                       \
    half8 ah_, al_;                                                          \
    _Pragma("unroll")                                                        \
    for (int q_ = 0; q_ < 8; q_++) {                                         \
        const float v_ = av_[q_];                                            \
        const _Float16 h_ = (_Float16)v_;                                    \
        ah_[q_] = h_;                                                        \
        al_[q_] = (_Float16)((v_ - (float)h_) * 4096.0f);                    \
    }                                                                        \
    _Pragma("unroll")                                                        \
    for (int t_ = 0; t_ < 4; t_++) {                                         \
        const half8 bh_ = *(const half8*)(buf_ + bOff[t_ * 2]);              \
        const half8 bl_ = *(const half8*)(buf_ + bOff[t_ * 2 + 1]);          \
        accH[t_] = __builtin_amdgcn_mfma_f32_16x16x32_f16(ah_, bh_, accH[t_], 0, 0, 0); \
        accC[t_] = __builtin_amdgcn_mfma_f32_16x16x32_f16(ah_, bl_, accC[t_], 0, 0, 0); \
        accC[t_] = __builtin_amdgcn_mfma_f32_16x16x32_f16(al_, bh_, accC[t_], 0, 0, 0); \
    }                                                                        \
    if (DOFOLD) {                                                            \
        _Pragma("unroll")                                                    \
        for (int t_ = 0; t_ < 4; t_++)                                       \
        _Pragma("unroll")                                                    \
        for (int r_ = 0; r_ < 4; r_++) {                                     \
            accD[t_][r_] += (double)accH[t_][r_] + (double)accC[t_][r_] * (1.0 / 4096.0); \
            accH[t_][r_] = 0.0f;                                             \
            accC[t_][r_] = 0.0f;                                             \
        }                                                                    \
    }                                                                        \
    asm volatile("s_waitcnt vmcnt(4)" ::: "memory");   /* loads(T+1) landed */\
    unsigned char* wb_ = smem + (WB) * BUF_BYTES;                            \
    _Pragma("unroll")                                                        \
    for (int i_ = 0; i_ < 4; i_++) *(float4*)(wb_ + dOff[i_]) = RW[i_];      \
    MEMFENCE;                                                                \
} while (0)

    for (int tt = 0; tt < 16; tt++) {
        ITER(RA, RB, 0, 1, 2 * tt,     false);          // even t
        ITER(RB, RA, 1, 0, 2 * tt + 1, (tt & 3) == 3);  // odd t: fold at t=7,15,23,31
    }
#undef ITER

    // drain tail loads, then cross-K-half fp64 reduce through aliased LDS
    asm volatile("s_waitcnt vmcnt(0)" ::: "memory");
    __syncthreads();

    double* red = (double*)smem;        // 4 tg * 64 lanes * 17 doubles = 34.8KB
    if (kh == 1) {
#pragma unroll
        for (int t = 0; t < 4; t++)
#pragma unroll
            for (int r = 0; r < 4; r++)
                red[(tg * 64 + lane) * 17 + t * 4 + r] = accD[t][r];
    }
    __syncthreads();
    if (kh == 1) return;

#pragma unroll
    for (int t = 0; t < 4; t++)
#pragma unroll
        for (int r = 0; r < 4; r++)
            accD[t][r] += red[(tg * 64 + lane) * 17 + t * 4 + r];

    // ---- epilogue: per token row, softmax + top2 + combine + hist ----
    const int rowg = lane >> 4;
#pragma unroll
    for (int r = 0; r < 4; r++) {
        float lv[4];
#pragma unroll
        for (int t = 0; t < 4; t++) lv[t] = (float)(accD[t][r] * (1.0 / 64.0));

        float m = fmaxf(fmaxf(lv[0], lv[1]), fmaxf(lv[2], lv[3]));
#pragma unroll
        for (int d = 1; d < 16; d <<= 1) m = fmaxf(m, __shfl_xor(m, d));

        // local top2 over this lane's 4 experts (ascending index)
        float l1 = -INFINITY, l2 = -INFINITY;
        int i1 = 0, i2 = 0;
#pragma unroll
        for (int t = 0; t < 4; t++) {
            const float l = lv[t];
            const int e = t * 16 + col;
            if (l > l1)      { l2 = l1; i2 = i1; l1 = l; i1 = e; }
            else if (l > l2) { l2 = l;  i2 = e; }
        }
        // cross-lane top2 merge within the 16-lane row group (lowest-idx ties)
#pragma unroll
        for (int d = 1; d < 16; d <<= 1) {
            const float ol1 = __shfl_xor(l1, d), ol2 = __shfl_xor(l2, d);
            const int   oi1 = __shfl_xor(i1, d), oi2 = __shfl_xor(i2, d);
            if (ol1 > l1 || (ol1 == l1 && oi1 < i1)) {
                if (l1 > ol2 || (l1 == ol2 && i1 < oi2)) { l2 = l1;  i2 = i1;  }
                else                                     { l2 = ol2; i2 = oi2; }
                l1 = ol1; i1 = oi1;
            } else if (ol1 > l2 || (ol1 == l2 && oi1 < i2)) {
                l2 = ol1; i2 = oi1;
            }
        }

        float ex[4];
        double sd = 0.0;
#pragma unroll
        for (int t = 0; t < 4; t++) { ex[t] = expf(lv[t] - m); sd += (double)ex[t]; }
#pragma unroll
        for (int d = 1; d < 16; d <<= 1) sd += __shfl_xor(sd, d);
        const float inv = (float)(1.0 / sd);

        const int tok = t0 + tg * 16 + rowg * 4 + r;
        float* pp2 = out + OFF_PROBS + (size_t)tok * NUM_EXPERTS + col;
#pragma unroll
        for (int t = 0; t < 4; t++) pp2[t * 16] = ex[t] * inv;

        if (col == 0) {
            const float p1 = expf(l1 - m) * inv;
            const float p2 = expf(l2 - m) * inv;
            const float e2 = expf(p2 - p1);
            const float rr2 = 1.0f / (1.0f + e2);
            out[OFF_COMBINE + 2 * tok]     = rr2;
            out[OFF_COMBINE + 2 * tok + 1] = e2 * rr2;
            flat_idx[2 * tok]     = i1;
            flat_idx[2 * tok + 1] = i2;
            atomicAdd(&segHist[(tok >> 6) * NUM_EXPERTS + i1], 1);
            atomicAdd(&segHist[(tok >> 6) * NUM_EXPERTS + i2], 1);
        }
    }
}

// ---------------------------------------------------------------------------
// Kernel 3: fused scan + scatter. 128 blocks x 256 threads; each block
// redundantly computes the full segment-offset scan in LDS, then does the
// verified ballot-match stable scatter for its 256 (token,slot) entries.
// ---------------------------------------------------------------------------
__global__ __launch_bounds__(256) void scan_scatter(
    const int* __restrict__ flat_idx, const int* __restrict__ segHist,
    float* __restrict__ out)
{
    __shared__ int h[NSEG * NUM_EXPERTS];   // 64 KB
    __shared__ int gtot[4 * NUM_EXPERTS];
    __shared__ int base_[NUM_EXPERTS];
    __shared__ int cnt[2 * NUM_EXPERTS];

    const int tid = threadIdx.x;
    for (int i = tid; i < NSEG * NUM_EXPERTS / 4; i += 256)
        *(int4*)(h + i * 4) = *(const int4*)(segHist + i * 4);
    if (tid < 2 * NUM_EXPERTS) cnt[tid] = 0;
    __syncthreads();

    const int e = tid & 63;
    const int g = tid >> 6;                 // 0..3
    int run = 0;
    for (int s = g * 64; s < g * 64 + 64; s++) {
        const int idx = s * NUM_EXPERTS + e;
        const int v = h[idx];
        h[idx] = run;
        run += v;
    }
    gtot[g * NUM_EXPERTS + e] = run;
    __syncthreads();

    if (tid < NUM_EXPERTS) {
        int b = 0;
#pragma unroll
        for (int gg = 0; gg < 4; gg++) {
            const int t = gtot[gg * NUM_EXPERTS + tid];
            gtot[gg * NUM_EXPERTS + tid] = b;
            b += t;
        }
        if (blockIdx.x == 0) out[OFF_SPLITS + tid] = (float)b;
        int xs = b;                          // inclusive wave scan over experts
#pragma unroll
        for (int off = 1; off < 64; off <<= 1) {
            const int v = __shfl_up(xs, off);
            if (tid >= off) xs += v;
        }
        base_[tid] = xs - b;                 // exclusive
    }
    __syncthreads();

    // ---- scatter phase ----
    const int i = blockIdx.x * 256 + tid;
    const int ee = flat_idx[i];
    const int lane = tid & 63;
    const int wv = tid >> 6;
    const int segslot = wv >> 1;
    const int seg = i >> 7;

    unsigned long long match = ~0ull;
#pragma unroll
    for (int b = 0; b < 6; b++) {
        const unsigned long long m = __ballot((ee >> b) & 1);
        match &= ((ee >> b) & 1) ? m : ~m;
    }
    const int rank = __popcll(match & ((1ull << lane) - 1ull));

    const int segoff = h[seg * NUM_EXPERTS + ee]
                     + gtot[(seg >> 6) * NUM_EXPERTS + ee] + base_[ee];

    int pos = 0;
    if ((wv & 1) == 0) {
        pos = segoff + rank;
        if (lane == __builtin_ctzll(match))
            cnt[segslot * NUM_EXPERTS + ee] = __popcll(match);
    }
    __syncthreads();
    if ((wv & 1) == 1)
        pos = segoff + cnt[segslot * NUM_EXPERTS + ee] + rank;

    out[OFF_TOKEN_ORDER + pos] = (float)(i >> 1);
    out[OFF_REVERSED + i]      = (float)pos;
}

// ---------------------------------------------------------------------------
extern "C" void kernel_launch(void* const* d_in, const int* in_sizes, int n_in,
                              void* d_out, int out_size, void* d_ws, size_t ws_size,
                              hipStream_t stream) {
    const float* x = (const float*)d_in[0];   // [16384, 2048] fp32
    const float* w = (const float*)d_in[1];   // [64, 2048] fp32
    float* out = (float*)d_out;

    int* flat_idx = (int*)d_ws;                          // NK ints
    int* segHist  = flat_idx + NK;                       // 256*64 ints
    half8* WH = (half8*)(segHist + NSEG * NUM_EXPERTS);  // 16384 frags (256 KB)
    half8* WL = WH + NFRAG;                              // 256 KB

    preconvert<<<64, 256, 0, stream>>>(w, WH, WL, segHist);
    gate_fused<<<256, 512, 0, stream>>>(x, WH, WL, out, flat_idx, segHist);
    scan_scatter<<<NK / 256, 256, 0, stream>>>(flat_idx, segHist, out);
}

// Round 6
// 297.189 us; speedup vs baseline: 1.0787x; 1.0787x over previous
//
#include <hip/hip_runtime.h>
#include <math.h>

#define N_TOKENS    16384
#define MODEL_DIM   2048
#define NUM_EXPERTS 64
#define NK          (N_TOKENS * 2)          // 32768

// d_out layout (float32 elements)
#define OFF_TOKEN_ORDER 0
#define OFF_REVERSED    (NK)                // 32768
#define OFF_COMBINE     (2 * NK)            // 65536
#define OFF_SPLITS      (3 * NK)            // 98304
#define OFF_PROBS       (3 * NK + NUM_EXPERTS)

#define NSEG 256
#define NFRAG 16384            // 64 ksteps * 4 tiles * 64 lanes

#define BUF_BYTES 16384        // per kstep: B 8KB (8 chunks) + A 8KB (8 chunks)

typedef _Float16 half8 __attribute__((ext_vector_type(8)));
typedef float    f32x4 __attribute__((ext_vector_type(4)));

#define MEMFENCE asm volatile("" ::: "memory")

// ---------------------------------------------------------------------------
// Kernel 1: pre-split W into f16 hi/lo MFMA fragments (W scaled x64 so hi is
// never f16-denormal; lo is the x4096-scaled exact residual). Also zeroes
// segHist. Fragment fr = (kstep*4 + tile)*64 + lane holds 8 f16 of
// W[tile*16 + (lane&15)][kstep*32 + (lane>>4)*8 + 0..7].
// ---------------------------------------------------------------------------
__global__ __launch_bounds__(256) void preconvert(
    const float* __restrict__ w, half8* __restrict__ WH, half8* __restrict__ WL,
    int* __restrict__ segHist)
{
    const int fr = blockIdx.x * 256 + threadIdx.x;   // 0..16383
    const int lane = fr & 63;
    const int tile = (fr >> 6) & 3;
    const int kstep = fr >> 8;
    const int e = tile * 16 + (lane & 15);
    const int kb = kstep * 32 + (lane >> 4) * 8;
    const float* src = w + (size_t)e * MODEL_DIM + kb;
    const float4 w0 = *(const float4*)(src);
    const float4 w1 = *(const float4*)(src + 4);
    const float av[8] = {w0.x, w0.y, w0.z, w0.w, w1.x, w1.y, w1.z, w1.w};
    half8 hh, hl;
#pragma unroll
    for (int j = 0; j < 8; j++) {
        const float v = av[j] * 64.0f;
        const _Float16 h = (_Float16)v;
        hh[j] = h;
        hl[j] = (_Float16)((v - (float)h) * 4096.0f);
    }
    WH[fr] = hh;
    WL[fr] = hl;
    segHist[fr] = 0;        // NSEG*NUM_EXPERTS == 16384 exactly
}

// ---------------------------------------------------------------------------
// Kernel 2: fused gate v4 — traffic-minimal AND spill-free.
// Round-5 post-mortem: the dataflow was right (FETCH fell to 131MB) but
// __launch_bounds__(512,2) squeezed VGPRs to 56 -> pipeline + fp64 acc
// spilled to scratch (WRITE_SIZE 5MB->177MB). This version keeps the
// traffic-minimal design with a sane register budget:
//   - 256 blocks x 256 threads (4 waves). 64 tokens/block, NO K-split:
//     each wave owns 16 tokens over full K=2048 (64 ksteps) -> no cross-wave
//     reduce, no red[] LDS, ~32 fewer live VGPRs.
//   - B staged ONCE per block, shared by 4 waves: global traffic =
//     X 128MB (HBM, once) + B 256x512KB = 128MB (L2). Total 256MB.
//   - per kstep: 16KB = 16 contiguous 1KB chunks (8 B-frag + 8 A-row);
//     4 global_load_dwordx4/thread -> depth-2 RA/RB register pipeline,
//     counted vmcnt(4) (never drained in-loop), ONE s_barrier/kstep.
//   - A chunks: 8 rows x 128B, 16B pieces XOR-swizzled at the ds_write
//     (read side applies same XOR) -> exactly 8 lanes/bank-quad = b128
//     minimum, conflict-free.
//   - plain __launch_bounds__(256): no occupancy cap -> no spills (~140 VGPR).
// fp64 fold every 8 ksteps (=256 K, same cadence as all passing rounds);
// verified softmax/top2/combine/hist epilogue per wave.
// logit = (accH + accC/4096)/64, W pre-scaled x64.
// ---------------------------------------------------------------------------
__global__ __launch_bounds__(256) void gate_fused(
    const float* __restrict__ x, const half8* __restrict__ WH,
    const half8* __restrict__ WL, float* __restrict__ out,
    int* __restrict__ flat_idx, int* __restrict__ segHist)
{
    __shared__ alignas(16) unsigned char smem[2 * BUF_BYTES];   // 32KB

    const int tid  = threadIdx.x;
    const int wv   = tid >> 6;          // 0..3 (token-group AND staged B-tile)
    const int lane = tid & 63;
    const int t0   = blockIdx.x * 64;
    const int col  = lane & 15;
    const int kg   = lane >> 4;

    // ---- staging sources: 4 chunks/thread/kstep ----
    // i=0: B tile=wv hi ; i=1: B tile=wv lo ; i=2,3: A rows for own 16 tokens
    const int arow   = lane >> 3;       // 0..7
    const int apiece = lane & 7;        // 16B piece within 128B row
    const char* pSrc[4];
    pSrc[0] = (const char*)(WH + (size_t)wv * 64 + lane);
    pSrc[1] = (const char*)(WL + (size_t)wv * 64 + lane);
    pSrc[2] = (const char*)(x + (size_t)(t0 + wv * 16 + arow) * MODEL_DIM + apiece * 4);
    pSrc[3] = (const char*)(x + (size_t)(t0 + wv * 16 + 8 + arow) * MODEL_DIM + apiece * 4);
    const int sStr[4] = {4096, 4096, 128, 128};
    int dOff[4];
    {
        const int swz = arow * 128 + ((apiece ^ arow) << 4);   // write-side XOR
        dOff[0] = (wv * 2    ) * 1024 + lane * 16;             // B chunk 2*wv
        dOff[1] = (wv * 2 + 1) * 1024 + lane * 16;             // B chunk 2*wv+1
        dOff[2] = 8192 + wv * 2048 + swz;                      // A chunk 2*wv
        dOff[3] = 8192 + wv * 2048 + 1024 + swz;               // A chunk 2*wv+1
    }

    // ---- reader offsets ----
    // A: token row = col (within this wave's 16), pieces 2*kg, 2*kg+1
    const int rowin = col & 7;
    const int abase = 8192 + wv * 2048 + (col >> 3) * 1024 + rowin * 128;
    const int aoff0 = abase + (((2 * kg)     ^ rowin) << 4);
    const int aoff1 = abase + (((2 * kg + 1) ^ rowin) << 4);
    // B: tile t -> chunks 2t (hi), 2t+1 (lo), linear lane*16
    const int boff  = lane * 16;

    f32x4 accH[4], accC[4];
    double accD[4][4];
#pragma unroll
    for (int t = 0; t < 4; t++) {
        accH[t] = (f32x4){0.f, 0.f, 0.f, 0.f};
        accC[t] = (f32x4){0.f, 0.f, 0.f, 0.f};
#pragma unroll
        for (int r = 0; r < 4; r++) accD[t][r] = 0.0;
    }

    float4 RA[4], RB[4];

    // prologue: loads(0)->RA, loads(1)->RB, write RA->buf0
#pragma unroll
    for (int i = 0; i < 4; i++) RA[i] = *(const float4*)(pSrc[i]);
#pragma unroll
    for (int i = 0; i < 4; i++) RB[i] = *(const float4*)(pSrc[i] + sStr[i]);
    asm volatile("s_waitcnt vmcnt(4)" ::: "memory");           // loads(0) landed
#pragma unroll
    for (int i = 0; i < 4; i++) *(float4*)(smem + dOff[i]) = RA[i];

#define ITER(RI, RW, CB, WB, T, DOFOLD) do {                                 \
    const int jn_ = ((T) < 62) ? (T) + 2 : 63;                               \
    _Pragma("unroll")                                                        \
    for (int i_ = 0; i_ < 4; i_++)                                           \
        RI[i_] = *(const float4*)(pSrc[i_] + (size_t)jn_ * sStr[i_]);        \
    asm volatile("s_waitcnt lgkmcnt(0)" ::: "memory");                       \
    __builtin_amdgcn_s_barrier();                                            \
    MEMFENCE;                                                                \
    const unsigned char* buf_ = smem + (CB) * BUF_BYTES;                     \
    const float4 a0_ = *(const float4*)(buf_ + aoff0);                       \
    const float4 a1_ = *(const float4*)(buf_ + aoff1);                       \
    const float av_[8] = {a0_.x, a0_.y, a0_.z, a0_.w,                        \
                          a1_.x, a1_.y, a1_.z, a1_.w};                       \
    half8 ah_, al_;                                                          \
    _Pragma("unroll")                                                        \
    for (int q_ = 0; q_ < 8; q_++) {                                         \
        const float v_ = av_[q_];                                            \
        const _Float16 h_ = (_Float16)v_;                                    \
        ah_[q_] = h_;                                                        \
        al_[q_] = (_Float16)((v_ - (float)h_) * 4096.0f);                    \
    }                                                                        \
    _Pragma("unroll")                                                        \
    for (int t_ = 0; t_ < 4; t_++) {                                         \
        const half8 bh_ = *(const half8*)(buf_ + (2 * t_) * 1024 + boff);    \
        const half8 bl_ = *(const half8*)(buf_ + (2 * t_ + 1) * 1024 + boff);\
        accH[t_] = __builtin_amdgcn_mfma_f32_16x16x32_f16(ah_, bh_, accH[t_], 0, 0, 0); \
        accC[t_] = __builtin_amdgcn_mfma_f32_16x16x32_f16(ah_, bl_, accC[t_], 0, 0, 0); \
        accC[t_] = __builtin_amdgcn_mfma_f32_16x16x32_f16(al_, bh_, accC[t_], 0, 0, 0); \
    }                                                                        \
    if (DOFOLD) {                                                            \
        _Pragma("unroll")                                                    \
        for (int t_ = 0; t_ < 4; t_++)                                       \
        _Pragma("unroll")                                                    \
        for (int r_ = 0; r_ < 4; r_++) {                                     \
            accD[t_][r_] += (double)accH[t_][r_] + (double)accC[t_][r_] * (1.0 / 4096.0); \
            accH[t_][r_] = 0.0f;                                             \
            accC[t_][r_] = 0.0f;                                             \
        }                                                                    \
    }                                                                        \
    asm volatile("s_waitcnt vmcnt(4)" ::: "memory");   /* loads(T+1) landed */\
    unsigned char* wb_ = smem + (WB) * BUF_BYTES;                            \
    _Pragma("unroll")                                                        \
    for (int i_ = 0; i_ < 4; i_++) *(float4*)(wb_ + dOff[i_]) = RW[i_];      \
    MEMFENCE;                                                                \
} while (0)

    for (int tt = 0; tt < 32; tt++) {
        ITER(RA, RB, 0, 1, 2 * tt,     false);          // even kstep
        ITER(RB, RA, 1, 0, 2 * tt + 1, (tt & 3) == 3);  // odd: fold at 7,15,...,63
    }
#undef ITER

    // drain tail loads (redundant jn=63 restages; never read)
    asm volatile("s_waitcnt vmcnt(0)" ::: "memory");

    // ---- epilogue: per token row, softmax + top2 + combine + hist ----
    const int rowg = lane >> 4;
#pragma unroll
    for (int r = 0; r < 4; r++) {
        float lv[4];
#pragma unroll
        for (int t = 0; t < 4; t++) lv[t] = (float)(accD[t][r] * (1.0 / 64.0));

        float m = fmaxf(fmaxf(lv[0], lv[1]), fmaxf(lv[2], lv[3]));
#pragma unroll
        for (int d = 1; d < 16; d <<= 1) m = fmaxf(m, __shfl_xor(m, d));

        // local top2 over this lane's 4 experts (ascending index)
        float l1 = -INFINITY, l2 = -INFINITY;
        int i1 = 0, i2 = 0;
#pragma unroll
        for (int t = 0; t < 4; t++) {
            const float l = lv[t];
            const int e = t * 16 + col;
            if (l > l1)      { l2 = l1; i2 = i1; l1 = l; i1 = e; }
            else if (l > l2) { l2 = l;  i2 = e; }
        }
        // cross-lane top2 merge within the 16-lane row group (lowest-idx ties)
#pragma unroll
        for (int d = 1; d < 16; d <<= 1) {
            const float ol1 = __shfl_xor(l1, d), ol2 = __shfl_xor(l2, d);
            const int   oi1 = __shfl_xor(i1, d), oi2 = __shfl_xor(i2, d);
            if (ol1 > l1 || (ol1 == l1 && oi1 < i1)) {
                if (l1 > ol2 || (l1 == ol2 && i1 < oi2)) { l2 = l1;  i2 = i1;  }
                else                                     { l2 = ol2; i2 = oi2; }
                l1 = ol1; i1 = oi1;
            } else if (ol1 > l2 || (ol1 == l2 && oi1 < i2)) {
                l2 = ol1; i2 = oi1;
            }
        }

        float ex[4];
        double sd = 0.0;
#pragma unroll
        for (int t = 0; t < 4; t++) { ex[t] = expf(lv[t] - m); sd += (double)ex[t]; }
#pragma unroll
        for (int d = 1; d < 16; d <<= 1) sd += __shfl_xor(sd, d);
        const float inv = (float)(1.0 / sd);

        const int tok = t0 + wv * 16 + rowg * 4 + r;
        float* pp2 = out + OFF_PROBS + (size_t)tok * NUM_EXPERTS + col;
#pragma unroll
        for (int t = 0; t < 4; t++) pp2[t * 16] = ex[t] * inv;

        if (col == 0) {
            const float p1 = expf(l1 - m) * inv;
            const float p2 = expf(l2 - m) * inv;
            const float e2 = expf(p2 - p1);
            const float rr2 = 1.0f / (1.0f + e2);
            out[OFF_COMBINE + 2 * tok]     = rr2;
            out[OFF_COMBINE + 2 * tok + 1] = e2 * rr2;
            flat_idx[2 * tok]     = i1;
            flat_idx[2 * tok + 1] = i2;
            atomicAdd(&segHist[(tok >> 6) * NUM_EXPERTS + i1], 1);
            atomicAdd(&segHist[(tok >> 6) * NUM_EXPERTS + i2], 1);
        }
    }
}

// ---------------------------------------------------------------------------
// Kernel 3: fused scan + scatter. 128 blocks x 256 threads; each block
// redundantly computes the full segment-offset scan in LDS, then does the
// verified ballot-match stable scatter for its 256 (token,slot) entries.
// ---------------------------------------------------------------------------
__global__ __launch_bounds__(256) void scan_scatter(
    const int* __restrict__ flat_idx, const int* __restrict__ segHist,
    float* __restrict__ out)
{
    __shared__ int h[NSEG * NUM_EXPERTS];   // 64 KB
    __shared__ int gtot[4 * NUM_EXPERTS];
    __shared__ int base_[NUM_EXPERTS];
    __shared__ int cnt[2 * NUM_EXPERTS];

    const int tid = threadIdx.x;
    for (int i = tid; i < NSEG * NUM_EXPERTS / 4; i += 256)
        *(int4*)(h + i * 4) = *(const int4*)(segHist + i * 4);
    if (tid < 2 * NUM_EXPERTS) cnt[tid] = 0;
    __syncthreads();

    const int e = tid & 63;
    const int g = tid >> 6;                 // 0..3
    int run = 0;
    for (int s = g * 64; s < g * 64 + 64; s++) {
        const int idx = s * NUM_EXPERTS + e;
        const int v = h[idx];
        h[idx] = run;
        run += v;
    }
    gtot[g * NUM_EXPERTS + e] = run;
    __syncthreads();

    if (tid < NUM_EXPERTS) {
        int b = 0;
#pragma unroll
        for (int gg = 0; gg < 4; gg++) {
            const int t = gtot[gg * NUM_EXPERTS + tid];
            gtot[gg * NUM_EXPERTS + tid] = b;
            b += t;
        }
        if (blockIdx.x == 0) out[OFF_SPLITS + tid] = (float)b;
        int xs = b;                          // inclusive wave scan over experts
#pragma unroll
        for (int off = 1; off < 64; off <<= 1) {
            const int v = __shfl_up(xs, off);
            if (tid >= off) xs += v;
        }
        base_[tid] = xs - b;                 // exclusive
    }
    __syncthreads();

    // ---- scatter phase ----
    const int i = blockIdx.x * 256 + tid;
    const int ee = flat_idx[i];
    const int lane = tid & 63;
    const int wv = tid >> 6;
    const int segslot = wv >> 1;
    const int seg = i >> 7;

    unsigned long long match = ~0ull;
#pragma unroll
    for (int b = 0; b < 6; b++) {
        const unsigned long long m = __ballot((ee >> b) & 1);
        match &= ((ee >> b) & 1) ? m : ~m;
    }
    const int rank = __popcll(match & ((1ull << lane) - 1ull));

    const int segoff = h[seg * NUM_EXPERTS + ee]
                     + gtot[(seg >> 6) * NUM_EXPERTS + ee] + base_[ee];

    int pos = 0;
    if ((wv & 1) == 0) {
        pos = segoff + rank;
        if (lane == __builtin_ctzll(match))
            cnt[segslot * NUM_EXPERTS + ee] = __popcll(match);
    }
    __syncthreads();
    if ((wv & 1) == 1)
        pos = segoff + cnt[segslot * NUM_EXPERTS + ee] + rank;

    out[OFF_TOKEN_ORDER + pos] = (float)(i >> 1);
    out[OFF_REVERSED + i]      = (float)pos;
}

// ---------------------------------------------------------------------------
extern "C" void kernel_launch(void* const* d_in, const int* in_sizes, int n_in,
                              void* d_out, int out_size, void* d_ws, size_t ws_size,
                              hipStream_t stream) {
    const float* x = (const float*)d_in[0];   // [16384, 2048] fp32
    const float* w = (const float*)d_in[1];   // [64, 2048] fp32
    float* out = (float*)d_out;

    int* flat_idx = (int*)d_ws;                          // NK ints
    int* segHist  = flat_idx + NK;                       // 256*64 ints
    half8* WH = (half8*)(segHist + NSEG * NUM_EXPERTS);  // 16384 frags (256 KB)
    half8* WL = WH + NFRAG;                              // 256 KB

    preconvert<<<64, 256, 0, stream>>>(w, WH, WL, segHist);
    gate_fused<<<256, 256, 0, stream>>>(x, WH, WL, out, flat_idx, segHist);
    scan_scatter<<<NK / 256, 256, 0, stream>>>(flat_idx, segHist, out);
}

// Round 7
// 243.869 us; speedup vs baseline: 1.3146x; 1.2186x over previous
//
#include <hip/hip_runtime.h>
#include <math.h>

#define N_TOKENS    16384
#define MODEL_DIM   2048
#define NUM_EXPERTS 64
#define NK          (N_TOKENS * 2)          // 32768

// d_out layout (float32 elements)
#define OFF_TOKEN_ORDER 0
#define OFF_REVERSED    (NK)                // 32768
#define OFF_COMBINE     (2 * NK)            // 65536
#define OFF_SPLITS      (3 * NK)            // 98304
#define OFF_PROBS       (3 * NK + NUM_EXPERTS)

#define NSEG 256
#define NFRAG 16384            // 64 ksteps * 4 tiles * 64 lanes

typedef _Float16 half8 __attribute__((ext_vector_type(8)));
typedef float    f32x4 __attribute__((ext_vector_type(4)));
typedef double   d64x2 __attribute__((ext_vector_type(2)));

// ---------------------------------------------------------------------------
// Kernel 1: pre-split W into f16 hi/lo MFMA fragments (W scaled x64 so hi is
// never f16-denormal; lo is the x4096-scaled exact residual). Also zeroes
// segHist. Fragment fr = (kstep*4 + tile)*64 + lane holds 8 f16 of
// W[tile*16 + (lane&15)][kstep*32 + (lane>>4)*8 + 0..7].
// ---------------------------------------------------------------------------
__global__ __launch_bounds__(256) void preconvert(
    const float* __restrict__ w, half8* __restrict__ WH, half8* __restrict__ WL,
    int* __restrict__ segHist)
{
    const int fr = blockIdx.x * 256 + threadIdx.x;   // 0..16383
    const int lane = fr & 63;
    const int tile = (fr >> 6) & 3;
    const int kstep = fr >> 8;
    const int e = tile * 16 + (lane & 15);
    const int kb = kstep * 32 + (lane >> 4) * 8;
    const float* src = w + (size_t)e * MODEL_DIM + kb;
    const float4 w0 = *(const float4*)(src);
    const float4 w1 = *(const float4*)(src + 4);
    const float av[8] = {w0.x, w0.y, w0.z, w0.w, w1.x, w1.y, w1.z, w1.w};
    half8 hh, hl;
#pragma unroll
    for (int j = 0; j < 8; j++) {
        const float v = av[j] * 64.0f;
        const _Float16 h = (_Float16)v;
        hh[j] = h;
        hl[j] = (_Float16)((v - (float)h) * 4096.0f);
    }
    WH[fr] = hh;
    WL[fr] = hl;
    segHist[fr] = 0;        // NSEG*NUM_EXPERTS == 16384 exactly
}

// ---------------------------------------------------------------------------
// Kernel 2: split-K MFMA partial GEMM — max TLP, zero coupling.
// Rounds 1-6 post-mortem: traffic never correlated with time; wave count and
// barrier coupling did (r6: 1 wave/SIMD -> 154us; r0: 8 waves/SIMD VALU GEMM
// -> 60% busy). This kernel restores r0's concurrency with the MFMA datapath:
// grid (256 token-blocks, S=8 K-splits) x 4 waves = 8192 independent waves
// (8/SIMD). NO LDS, NO barriers, NO inline asm: per wave, 16 tokens x 64
// experts x K=256 (8 ksteps fully unrolled), plain global loads (A: 2
// dwordx4/lane strided; B: 8 contiguous-1KB frag loads, L1/L2-shared across
// the block's 4 waves), 12 MFMA/step, compiler-scheduled.
// At slice end: ONE fp64 fold (== the verified every-256-K cadence) stored as
// fp64 partials [slot=(tb*4+wv)*S+sp][16x64]. Reduce sums slices in sp order
// -> arithmetic BIT-IDENTICAL to the passing rounds.
// ---------------------------------------------------------------------------
template<int NS>
__global__ __launch_bounds__(256) void gate_partial(
    const float* __restrict__ x, const half8* __restrict__ WH,
    const half8* __restrict__ WL, double* __restrict__ part, int S)
{
    const int tid  = threadIdx.x;
    const int wv   = tid >> 6;
    const int lane = tid & 63;
    const int tb   = blockIdx.x;
    const int sp   = blockIdx.y;
    const int col  = lane & 15;
    const int kg   = lane >> 4;

    const float* pA = x + (size_t)(tb * 64 + wv * 16 + col) * MODEL_DIM
                    + (size_t)sp * NS * 32 + kg * 8;
    const size_t fb = (size_t)sp * NS * 4 * 64 + lane;
    const half8* pbh = WH + fb;
    const half8* pbl = WL + fb;

    f32x4 accH[4], accC[4];
    double accD[4][4];
#pragma unroll
    for (int t = 0; t < 4; t++) {
        accH[t] = (f32x4){0.f, 0.f, 0.f, 0.f};
        accC[t] = (f32x4){0.f, 0.f, 0.f, 0.f};
#pragma unroll
        for (int r = 0; r < 4; r++) accD[t][r] = 0.0;
    }

#pragma unroll
    for (int j = 0; j < NS; j++) {
        const float4 a0 = *(const float4*)(pA + j * 32);
        const float4 a1 = *(const float4*)(pA + j * 32 + 4);
        const float av[8] = {a0.x, a0.y, a0.z, a0.w, a1.x, a1.y, a1.z, a1.w};
        half8 ah, al;
#pragma unroll
        for (int q = 0; q < 8; q++) {
            const float v = av[q];
            const _Float16 h = (_Float16)v;
            ah[q] = h;
            al[q] = (_Float16)((v - (float)h) * 4096.0f);
        }
#pragma unroll
        for (int t = 0; t < 4; t++) {
            const half8 bh = pbh[(j * 4 + t) * 64];
            const half8 bl = pbl[(j * 4 + t) * 64];
            accH[t] = __builtin_amdgcn_mfma_f32_16x16x32_f16(ah, bh, accH[t], 0, 0, 0);
            accC[t] = __builtin_amdgcn_mfma_f32_16x16x32_f16(ah, bl, accC[t], 0, 0, 0);
            accC[t] = __builtin_amdgcn_mfma_f32_16x16x32_f16(al, bh, accC[t], 0, 0, 0);
        }
        if ((j & 7) == 7) {     // fp64 fold every 256 K (verified cadence)
#pragma unroll
            for (int t = 0; t < 4; t++)
#pragma unroll
                for (int r = 0; r < 4; r++) {
                    accD[t][r] += (double)accH[t][r] + (double)accC[t][r] * (1.0 / 4096.0);
                    accH[t][r] = 0.0f;
                    accC[t][r] = 0.0f;
                }
        }
    }

    double* dst = part + ((size_t)(tb * 4 + wv) * S + sp) * 1024 + (size_t)lane * 4;
#pragma unroll
    for (int t = 0; t < 4; t++) {
        *(d64x2*)(dst + t * 256)     = (d64x2){accD[t][0], accD[t][1]};
        *(d64x2*)(dst + t * 256 + 2) = (d64x2){accD[t][2], accD[t][3]};
    }
}

// ---------------------------------------------------------------------------
// Kernel 3: reduce fp64 partials over S slices (sp order == chronological K
// order -> bit-identical to the passing kernels' sequential folds), then the
// verified softmax/top2/combine/hist epilogue per 16-lane row group.
// 256 blocks x 256 threads; thread (wv,lane) owns the same fragment it had
// in gate_partial; loads are lane-contiguous (coalesced d64x2).
// ---------------------------------------------------------------------------
__global__ __launch_bounds__(256) void reduce_kernel(
    const double* __restrict__ part, float* __restrict__ out,
    int* __restrict__ flat_idx, int* __restrict__ segHist, int S)
{
    const int tid  = threadIdx.x;
    const int wv   = tid >> 6;
    const int lane = tid & 63;
    const int tb   = blockIdx.x;
    const int t0   = tb * 64;
    const int col  = lane & 15;

    const double* src = part + ((size_t)(tb * 4 + wv) * S) * 1024 + (size_t)lane * 4;

    double accD[4][4];
#pragma unroll
    for (int t = 0; t < 4; t++)
#pragma unroll
        for (int r = 0; r < 4; r++) accD[t][r] = 0.0;

    for (int sp = 0; sp < S; sp++) {
#pragma unroll
        for (int t = 0; t < 4; t++) {
            const d64x2 v0 = *(const d64x2*)(src + (size_t)sp * 1024 + t * 256);
            const d64x2 v1 = *(const d64x2*)(src + (size_t)sp * 1024 + t * 256 + 2);
            accD[t][0] += v0[0]; accD[t][1] += v0[1];
            accD[t][2] += v1[0]; accD[t][3] += v1[1];
        }
    }

    // ---- epilogue: per token row, softmax + top2 + combine + hist ----
    const int rowg = lane >> 4;
#pragma unroll
    for (int r = 0; r < 4; r++) {
        float lv[4];
#pragma unroll
        for (int t = 0; t < 4; t++) lv[t] = (float)(accD[t][r] * (1.0 / 64.0));

        float m = fmaxf(fmaxf(lv[0], lv[1]), fmaxf(lv[2], lv[3]));
#pragma unroll
        for (int d = 1; d < 16; d <<= 1) m = fmaxf(m, __shfl_xor(m, d));

        // local top2 over this lane's 4 experts (ascending index)
        float l1 = -INFINITY, l2 = -INFINITY;
        int i1 = 0, i2 = 0;
#pragma unroll
        for (int t = 0; t < 4; t++) {
            const float l = lv[t];
            const int e = t * 16 + col;
            if (l > l1)      { l2 = l1; i2 = i1; l1 = l; i1 = e; }
            else if (l > l2) { l2 = l;  i2 = e; }
        }
        // cross-lane top2 merge within the 16-lane row group (lowest-idx ties)
#pragma unroll
        for (int d = 1; d < 16; d <<= 1) {
            const float ol1 = __shfl_xor(l1, d), ol2 = __shfl_xor(l2, d);
            const int   oi1 = __shfl_xor(i1, d), oi2 = __shfl_xor(i2, d);
            if (ol1 > l1 || (ol1 == l1 && oi1 < i1)) {
                if (l1 > ol2 || (l1 == ol2 && i1 < oi2)) { l2 = l1;  i2 = i1;  }
                else                                     { l2 = ol2; i2 = oi2; }
                l1 = ol1; i1 = oi1;
            } else if (ol1 > l2 || (ol1 == l2 && oi1 < i2)) {
                l2 = ol1; i2 = oi1;
            }
        }

        float ex[4];
        double sd = 0.0;
#pragma unroll
        for (int t = 0; t < 4; t++) { ex[t] = expf(lv[t] - m); sd += (double)ex[t]; }
#pragma unroll
        for (int d = 1; d < 16; d <<= 1) sd += __shfl_xor(sd, d);
        const float inv = (float)(1.0 / sd);

        const int tok = t0 + wv * 16 + rowg * 4 + r;
        float* pp2 = out + OFF_PROBS + (size_t)tok * NUM_EXPERTS + col;
#pragma unroll
        for (int t = 0; t < 4; t++) pp2[t * 16] = ex[t] * inv;

        if (col == 0) {
            const float p1 = expf(l1 - m) * inv;
            const float p2 = expf(l2 - m) * inv;
            const float e2 = expf(p2 - p1);
            const float rr2 = 1.0f / (1.0f + e2);
            out[OFF_COMBINE + 2 * tok]     = rr2;
            out[OFF_COMBINE + 2 * tok + 1] = e2 * rr2;
            flat_idx[2 * tok]     = i1;
            flat_idx[2 * tok + 1] = i2;
            atomicAdd(&segHist[(tok >> 6) * NUM_EXPERTS + i1], 1);
            atomicAdd(&segHist[(tok >> 6) * NUM_EXPERTS + i2], 1);
        }
    }
}

// ---------------------------------------------------------------------------
// Kernel 4: fused scan + scatter. 128 blocks x 256 threads; each block
// redundantly computes the full segment-offset scan in LDS, then does the
// verified ballot-match stable scatter for its 256 (token,slot) entries.
// ---------------------------------------------------------------------------
__global__ __launch_bounds__(256) void scan_scatter(
    const int* __restrict__ flat_idx, const int* __restrict__ segHist,
    float* __restrict__ out)
{
    __shared__ int h[NSEG * NUM_EXPERTS];   // 64 KB
    __shared__ int gtot[4 * NUM_EXPERTS];
    __shared__ int base_[NUM_EXPERTS];
    __shared__ int cnt[2 * NUM_EXPERTS];

    const int tid = threadIdx.x;
    for (int i = tid; i < NSEG * NUM_EXPERTS / 4; i += 256)
        *(int4*)(h + i * 4) = *(const int4*)(segHist + i * 4);
    if (tid < 2 * NUM_EXPERTS) cnt[tid] = 0;
    __syncthreads();

    const int e = tid & 63;
    const int g = tid >> 6;                 // 0..3
    int run = 0;
    for (int s = g * 64; s < g * 64 + 64; s++) {
        const int idx = s * NUM_EXPERTS + e;
        const int v = h[idx];
        h[idx] = run;
        run += v;
    }
    gtot[g * NUM_EXPERTS + e] = run;
    __syncthreads();

    if (tid < NUM_EXPERTS) {
        int b = 0;
#pragma unroll
        for (int gg = 0; gg < 4; gg++) {
            const int t = gtot[gg * NUM_EXPERTS + tid];
            gtot[gg * NUM_EXPERTS + tid] = b;
            b += t;
        }
        if (blockIdx.x == 0) out[OFF_SPLITS + tid] = (float)b;
        int xs = b;                          // inclusive wave scan over experts
#pragma unroll
        for (int off = 1; off < 64; off <<= 1) {
            const int v = __shfl_up(xs, off);
            if (tid >= off) xs += v;
        }
        base_[tid] = xs - b;                 // exclusive
    }
    __syncthreads();

    // ---- scatter phase ----
    const int i = blockIdx.x * 256 + tid;
    const int ee = flat_idx[i];
    const int lane = tid & 63;
    const int wv = tid >> 6;
    const int segslot = wv >> 1;
    const int seg = i >> 7;

    unsigned long long match = ~0ull;
#pragma unroll
    for (int b = 0; b < 6; b++) {
        const unsigned long long m = __ballot((ee >> b) & 1);
        match &= ((ee >> b) & 1) ? m : ~m;
    }
    const int rank = __popcll(match & ((1ull << lane) - 1ull));

    const int segoff = h[seg * NUM_EXPERTS + ee]
                     + gtot[(seg >> 6) * NUM_EXPERTS + ee] + base_[ee];

    int pos = 0;
    if ((wv & 1) == 0) {
        pos = segoff + rank;
        if (lane == __builtin_ctzll(match))
            cnt[segslot * NUM_EXPERTS + ee] = __popcll(match);
    }
    __syncthreads();
    if ((wv & 1) == 1)
        pos = segoff + cnt[segslot * NUM_EXPERTS + ee] + rank;

    out[OFF_TOKEN_ORDER + pos] = (float)(i >> 1);
    out[OFF_REVERSED + i]      = (float)pos;
}

// ---------------------------------------------------------------------------
extern "C" void kernel_launch(void* const* d_in, const int* in_sizes, int n_in,
                              void* d_out, int out_size, void* d_ws, size_t ws_size,
                              hipStream_t stream) {
    const float* x = (const float*)d_in[0];   // [16384, 2048] fp32
    const float* w = (const float*)d_in[1];   // [64, 2048] fp32
    float* out = (float*)d_out;

    int* flat_idx = (int*)d_ws;                          // 128 KB
    int* segHist  = flat_idx + NK;                       // 64 KB
    half8* WH = (half8*)(segHist + NSEG * NUM_EXPERTS);  // 256 KB
    half8* WL = WH + NFRAG;                              // 256 KB
    double* part = (double*)(WL + NFRAG);

    const size_t fixed_bytes = (size_t)NK * 4 + NSEG * NUM_EXPERTS * 4
                             + 2 * (size_t)NFRAG * 16;
    const size_t avail = ws_size > fixed_bytes ? ws_size - fixed_bytes : 0;
    const size_t per = (size_t)N_TOKENS * NUM_EXPERTS * 8;   // 8 MB per split

    int S;
    if      (avail >= 8 * per) S = 8;
    else if (avail >= 4 * per) S = 4;
    else if (avail >= 2 * per) S = 2;
    else                       S = 1;

    preconvert<<<64, 256, 0, stream>>>(w, WH, WL, segHist);
    switch (S) {
        case 8: gate_partial<8> <<<dim3(256, 8), 256, 0, stream>>>(x, WH, WL, part, 8); break;
        case 4: gate_partial<16><<<dim3(256, 4), 256, 0, stream>>>(x, WH, WL, part, 4); break;
        case 2: gate_partial<32><<<dim3(256, 2), 256, 0, stream>>>(x, WH, WL, part, 2); break;
        default: gate_partial<64><<<dim3(256, 1), 256, 0, stream>>>(x, WH, WL, part, 1); break;
    }
    reduce_kernel<<<256, 256, 0, stream>>>(part, out, flat_idx, segHist, S);
    scan_scatter<<<NK / 256, 256, 0, stream>>>(flat_idx, segHist, out);
}

// Round 8
// 243.138 us; speedup vs baseline: 1.3186x; 1.0030x over previous
//
#include <hip/hip_runtime.h>
#include <math.h>

#define N_TOKENS    16384
#define MODEL_DIM   2048
#define NUM_EXPERTS 64
#define NK          (N_TOKENS * 2)          // 32768

// d_out layout (float32 elements)
#define OFF_TOKEN_ORDER 0
#define OFF_REVERSED    (NK)                // 32768
#define OFF_COMBINE     (2 * NK)            // 65536
#define OFF_SPLITS      (3 * NK)            // 98304
#define OFF_PROBS       (3 * NK + NUM_EXPERTS)

#define NSEG 256

typedef _Float16 half8 __attribute__((ext_vector_type(8)));
typedef float    f32x4 __attribute__((ext_vector_type(4)));
typedef double   d64x2 __attribute__((ext_vector_type(2)));

// exact 2-term f16 split of s*v (s=64 for W, 1 for A) — identical arithmetic
// to the verified preconvert/gate of rounds 1-7.
__device__ __forceinline__ void fsplit(const float4 a, const float4 b, const float s,
                                       half8& hh, half8& hl) {
    const float av[8] = {a.x, a.y, a.z, a.w, b.x, b.y, b.z, b.w};
#pragma unroll
    for (int q = 0; q < 8; q++) {
        const float v = av[q] * s;
        const _Float16 h = (_Float16)v;
        hh[q] = h;
        hl[q] = (_Float16)((v - (float)h) * 4096.0f);
    }
}

// ---------------------------------------------------------------------------
// Kernel 1: split-K MFMA partial GEMM — VMEM-byte-minimized, register-freed.
// Model from rounds 2-7: time ≈ VMEM-instruction-bytes / ~8 TB/s; nothing
// else moved the needle. Bytes here: A 128MB + B 256MB (32 tokens/wave halves
// r7's per-wave B re-read) + partials 64MB = 448MB (r7: 640MB).
// Grid (128 token-blocks, S=8 K-splits) x 256 threads (4 waves) = 4096
// independent waves, no LDS, no barriers. Wave = 32 tokens (2 row-tiles) x
// 64 experts x K=NS*32. B is split from w in-registers (fp32 read = same
// bytes as f16 hi+lo pair; kills the preconvert dispatch), A split unscaled —
// both bit-identical to the verified rounds. amdgpu_waves_per_eu(2,2) pins
// the allocator at 2 waves/SIMD (256-reg budget) so the occupancy-greedy
// scheduler stops serializing load-use chains (the VGPR=56 pathology of
// r5/r6/r7). fp64 fold every 8 ksteps (=256 K, verified cadence); partials
// stored fp64, summed by reduce in sp order -> bit-identical numerics.
// ---------------------------------------------------------------------------
template<int NS>
__global__ __attribute__((amdgpu_waves_per_eu(2, 2))) __launch_bounds__(256)
void gate_partial(
    const float* __restrict__ x, const float* __restrict__ w,
    double* __restrict__ part, int S, int* __restrict__ segHist)
{
    const int tid  = threadIdx.x;
    const int wv   = tid >> 6;
    const int lane = tid & 63;
    const int tb   = blockIdx.x;        // 0..127 (128 tokens each)
    const int sp   = blockIdx.y;        // 0..S-1
    const int col  = lane & 15;
    const int kg   = lane >> 4;

    if (sp == 0 && tid < 128) segHist[tb * 128 + tid] = 0;   // 128*128 = 16384

    const int kbase = sp * NS * 32 + kg * 8;
    const float* pA0 = x + (size_t)(tb * 128 + wv * 32 + col) * MODEL_DIM + kbase;
    const float* pA1 = pA0 + (size_t)16 * MODEL_DIM;
    const float* pB  = w + (size_t)col * MODEL_DIM + kbase;  // + kt*16*2048 + j*32

    f32x4 accH[2][4], accC[2][4];
    double accD[2][4][4];
#pragma unroll
    for (int tt = 0; tt < 2; tt++)
#pragma unroll
        for (int t = 0; t < 4; t++) {
            accH[tt][t] = (f32x4){0.f, 0.f, 0.f, 0.f};
            accC[tt][t] = (f32x4){0.f, 0.f, 0.f, 0.f};
#pragma unroll
            for (int r = 0; r < 4; r++) accD[tt][t][r] = 0.0;
        }

#pragma unroll
    for (int j = 0; j < NS; j++) {
        const float4 a00 = *(const float4*)(pA0 + j * 32);
        const float4 a01 = *(const float4*)(pA0 + j * 32 + 4);
        const float4 a10 = *(const float4*)(pA1 + j * 32);
        const float4 a11 = *(const float4*)(pA1 + j * 32 + 4);
        half8 ah[2], al[2];
        fsplit(a00, a01, 1.0f, ah[0], al[0]);
        fsplit(a10, a11, 1.0f, ah[1], al[1]);

#pragma unroll
        for (int kt = 0; kt < 4; kt++) {
            const float4 b0 = *(const float4*)(pB + (size_t)kt * 16 * MODEL_DIM + j * 32);
            const float4 b1 = *(const float4*)(pB + (size_t)kt * 16 * MODEL_DIM + j * 32 + 4);
            half8 bh, bl;
            fsplit(b0, b1, 64.0f, bh, bl);
#pragma unroll
            for (int tt = 0; tt < 2; tt++) {
                accH[tt][kt] = __builtin_amdgcn_mfma_f32_16x16x32_f16(ah[tt], bh, accH[tt][kt], 0, 0, 0);
                accC[tt][kt] = __builtin_amdgcn_mfma_f32_16x16x32_f16(ah[tt], bl, accC[tt][kt], 0, 0, 0);
                accC[tt][kt] = __builtin_amdgcn_mfma_f32_16x16x32_f16(al[tt], bh, accC[tt][kt], 0, 0, 0);
            }
        }

        if ((j & 7) == 7) {     // fp64 fold every 256 K (verified cadence)
#pragma unroll
            for (int tt = 0; tt < 2; tt++)
#pragma unroll
                for (int t = 0; t < 4; t++)
#pragma unroll
                    for (int r = 0; r < 4; r++) {
                        accD[tt][t][r] += (double)accH[tt][t][r]
                                        + (double)accC[tt][t][r] * (1.0 / 4096.0);
                        accH[tt][t][r] = 0.0f;
                        accC[tt][t][r] = 0.0f;
                    }
        }
    }

#pragma unroll
    for (int tt = 0; tt < 2; tt++) {
        const int tile = tb * 8 + wv * 2 + tt;          // global 16-token tile
        double* dst = part + ((size_t)tile * S + sp) * 1024 + (size_t)lane * 4;
#pragma unroll
        for (int t = 0; t < 4; t++) {
            *(d64x2*)(dst + t * 256)     = (d64x2){accD[tt][t][0], accD[tt][t][1]};
            *(d64x2*)(dst + t * 256 + 2) = (d64x2){accD[tt][t][2], accD[tt][t][3]};
        }
    }
}

// ---------------------------------------------------------------------------
// Kernel 2: reduce fp64 partials over S slices (sp order == chronological K
// order -> bit-identical to the sequential folds), then the verified
// softmax/top2/combine/hist epilogue per 16-lane row group. (r7, unchanged)
// ---------------------------------------------------------------------------
__global__ __launch_bounds__(256) void reduce_kernel(
    const double* __restrict__ part, float* __restrict__ out,
    int* __restrict__ flat_idx, int* __restrict__ segHist, int S)
{
    const int tid  = threadIdx.x;
    const int wv   = tid >> 6;
    const int lane = tid & 63;
    const int tb   = blockIdx.x;
    const int t0   = tb * 64;
    const int col  = lane & 15;

    const double* src = part + ((size_t)(tb * 4 + wv) * S) * 1024 + (size_t)lane * 4;

    double accD[4][4];
#pragma unroll
    for (int t = 0; t < 4; t++)
#pragma unroll
        for (int r = 0; r < 4; r++) accD[t][r] = 0.0;

    for (int sp = 0; sp < S; sp++) {
#pragma unroll
        for (int t = 0; t < 4; t++) {
            const d64x2 v0 = *(const d64x2*)(src + (size_t)sp * 1024 + t * 256);
            const d64x2 v1 = *(const d64x2*)(src + (size_t)sp * 1024 + t * 256 + 2);
            accD[t][0] += v0[0]; accD[t][1] += v0[1];
            accD[t][2] += v1[0]; accD[t][3] += v1[1];
        }
    }

    // ---- epilogue: per token row, softmax + top2 + combine + hist ----
    const int rowg = lane >> 4;
#pragma unroll
    for (int r = 0; r < 4; r++) {
        float lv[4];
#pragma unroll
        for (int t = 0; t < 4; t++) lv[t] = (float)(accD[t][r] * (1.0 / 64.0));

        float m = fmaxf(fmaxf(lv[0], lv[1]), fmaxf(lv[2], lv[3]));
#pragma unroll
        for (int d = 1; d < 16; d <<= 1) m = fmaxf(m, __shfl_xor(m, d));

        // local top2 over this lane's 4 experts (ascending index)
        float l1 = -INFINITY, l2 = -INFINITY;
        int i1 = 0, i2 = 0;
#pragma unroll
        for (int t = 0; t < 4; t++) {
            const float l = lv[t];
            const int e = t * 16 + col;
            if (l > l1)      { l2 = l1; i2 = i1; l1 = l; i1 = e; }
            else if (l > l2) { l2 = l;  i2 = e; }
        }
        // cross-lane top2 merge within the 16-lane row group (lowest-idx ties)
#pragma unroll
        for (int d = 1; d < 16; d <<= 1) {
            const float ol1 = __shfl_xor(l1, d), ol2 = __shfl_xor(l2, d);
            const int   oi1 = __shfl_xor(i1, d), oi2 = __shfl_xor(i2, d);
            if (ol1 > l1 || (ol1 == l1 && oi1 < i1)) {
                if (l1 > ol2 || (l1 == ol2 && i1 < oi2)) { l2 = l1;  i2 = i1;  }
                else                                     { l2 = ol2; i2 = oi2; }
                l1 = ol1; i1 = oi1;
            } else if (ol1 > l2 || (ol1 == l2 && oi1 < i2)) {
                l2 = ol1; i2 = oi1;
            }
        }

        float ex[4];
        double sd = 0.0;
#pragma unroll
        for (int t = 0; t < 4; t++) { ex[t] = expf(lv[t] - m); sd += (double)ex[t]; }
#pragma unroll
        for (int d = 1; d < 16; d <<= 1) sd += __shfl_xor(sd, d);
        const float inv = (float)(1.0 / sd);

        const int tok = t0 + wv * 16 + rowg * 4 + r;
        float* pp2 = out + OFF_PROBS + (size_t)tok * NUM_EXPERTS + col;
#pragma unroll
        for (int t = 0; t < 4; t++) pp2[t * 16] = ex[t] * inv;

        if (col == 0) {
            const float p1 = expf(l1 - m) * inv;
            const float p2 = expf(l2 - m) * inv;
            const float e2 = expf(p2 - p1);
            const float rr2 = 1.0f / (1.0f + e2);
            out[OFF_COMBINE + 2 * tok]     = rr2;
            out[OFF_COMBINE + 2 * tok + 1] = e2 * rr2;
            flat_idx[2 * tok]     = i1;
            flat_idx[2 * tok + 1] = i2;
            atomicAdd(&segHist[(tok >> 6) * NUM_EXPERTS + i1], 1);
            atomicAdd(&segHist[(tok >> 6) * NUM_EXPERTS + i2], 1);
        }
    }
}

// ---------------------------------------------------------------------------
// Kernel 3: fused scan + scatter. 128 blocks x 256 threads; each block
// redundantly computes the full segment-offset scan in LDS, then does the
// verified ballot-match stable scatter for its 256 (token,slot) entries.
// (r4-r7, unchanged)
// ---------------------------------------------------------------------------
__global__ __launch_bounds__(256) void scan_scatter(
    const int* __restrict__ flat_idx, const int* __restrict__ segHist,
    float* __restrict__ out)
{
    __shared__ int h[NSEG * NUM_EXPERTS];   // 64 KB
    __shared__ int gtot[4 * NUM_EXPERTS];
    __shared__ int base_[NUM_EXPERTS];
    __shared__ int cnt[2 * NUM_EXPERTS];

    const int tid = threadIdx.x;
    for (int i = tid; i < NSEG * NUM_EXPERTS / 4; i += 256)
        *(int4*)(h + i * 4) = *(const int4*)(segHist + i * 4);
    if (tid < 2 * NUM_EXPERTS) cnt[tid] = 0;
    __syncthreads();

    const int e = tid & 63;
    const int g = tid >> 6;                 // 0..3
    int run = 0;
    for (int s = g * 64; s < g * 64 + 64; s++) {
        const int idx = s * NUM_EXPERTS + e;
        const int v = h[idx];
        h[idx] = run;
        run += v;
    }
    gtot[g * NUM_EXPERTS + e] = run;
    __syncthreads();

    if (tid < NUM_EXPERTS) {
        int b = 0;
#pragma unroll
        for (int gg = 0; gg < 4; gg++) {
            const int t = gtot[gg * NUM_EXPERTS + tid];
            gtot[gg * NUM_EXPERTS + tid] = b;
            b += t;
        }
        if (blockIdx.x == 0) out[OFF_SPLITS + tid] = (float)b;
        int xs = b;                          // inclusive wave scan over experts
#pragma unroll
        for (int off = 1; off < 64; off <<= 1) {
            const int v = __shfl_up(xs, off);
            if (tid >= off) xs += v;
        }
        base_[tid] = xs - b;                 // exclusive
    }
    __syncthreads();

    // ---- scatter phase ----
    const int i = blockIdx.x * 256 + tid;
    const int ee = flat_idx[i];
    const int lane = tid & 63;
    const int wv = tid >> 6;
    const int segslot = wv >> 1;
    const int seg = i >> 7;

    unsigned long long match = ~0ull;
#pragma unroll
    for (int b = 0; b < 6; b++) {
        const unsigned long long m = __ballot((ee >> b) & 1);
        match &= ((ee >> b) & 1) ? m : ~m;
    }
    const int rank = __popcll(match & ((1ull << lane) - 1ull));

    const int segoff = h[seg * NUM_EXPERTS + ee]
                     + gtot[(seg >> 6) * NUM_EXPERTS + ee] + base_[ee];

    int pos = 0;
    if ((wv & 1) == 0) {
        pos = segoff + rank;
        if (lane == __builtin_ctzll(match))
            cnt[segslot * NUM_EXPERTS + ee] = __popcll(match);
    }
    __syncthreads();
    if ((wv & 1) == 1)
        pos = segoff + cnt[segslot * NUM_EXPERTS + ee] + rank;

    out[OFF_TOKEN_ORDER + pos] = (float)(i >> 1);
    out[OFF_REVERSED + i]      = (float)pos;
}

// ---------------------------------------------------------------------------
extern "C" void kernel_launch(void* const* d_in, const int* in_sizes, int n_in,
                              void* d_out, int out_size, void* d_ws, size_t ws_size,
                              hipStream_t stream) {
    const float* x = (const float*)d_in[0];   // [16384, 2048] fp32
    const float* w = (const float*)d_in[1];   // [64, 2048] fp32
    float* out = (float*)d_out;

    int* flat_idx = (int*)d_ws;                          // 128 KB
    int* segHist  = flat_idx + NK;                       // 64 KB
    double* part  = (double*)(segHist + NSEG * NUM_EXPERTS);

    const size_t fixed_bytes = (size_t)NK * 4 + NSEG * NUM_EXPERTS * 4;
    const size_t avail = ws_size > fixed_bytes ? ws_size - fixed_bytes : 0;
    const size_t per = (size_t)N_TOKENS * NUM_EXPERTS * 8;   // 8 MB per split

    int S;
    if      (avail >= 8 * per) S = 8;
    else if (avail >= 4 * per) S = 4;
    else if (avail >= 2 * per) S = 2;
    else                       S = 1;

    switch (S) {
        case 8: gate_partial<8> <<<dim3(128, 8), 256, 0, stream>>>(x, w, part, 8, segHist); break;
        case 4: gate_partial<16><<<dim3(128, 4), 256, 0, stream>>>(x, w, part, 4, segHist); break;
        case 2: gate_partial<32><<<dim3(128, 2), 256, 0, stream>>>(x, w, part, 2, segHist); break;
        default: gate_partial<64><<<dim3(128, 1), 256, 0, stream>>>(x, w, part, 1, segHist); break;
    }
    reduce_kernel<<<256, 256, 0, stream>>>(part, out, flat_idx, segHist, S);
    scan_scatter<<<NK / 256, 256, 0, stream>>>(flat_idx, segHist, out);
}